// Round 1
// baseline (947.514 us; speedup 1.0000x reference)
//
#include <hip/hip_runtime.h>
#include <hip/hip_bf16.h>
#include <cstdint>

// ---------------- static problem config ----------------
#define D_MODEL   256
#define N_HEADS   8
#define N_LEVELS  4
#define N_POINTS  4
#define D_FFN     1024
#define D_HEAD    32
#define LEN_IN    13294          // 100*100 + 50*50 + 25*25 + 13*13
#define NBATCH    2
#define M_TOK     (NBATCH * LEN_IN)   // 26588

__constant__ int c_lvl_h[4] = {100, 50, 25, 13};
__constant__ int c_lvl_w[4] = {100, 50, 25, 13};
__constant__ int c_lvl_s[4] = {0, 10000, 12500, 13125};

// ---------------- tiled fp32 GEMM ----------------
// C[M,N] = act( (A (+A2)) @ B + bias )
// A row-major [M,K], B row-major [K,N]. BM=BN=64, BK=16, 256 thr, 4x4/thread.
template <bool ADD2, bool RELU>
__global__ __launch_bounds__(256) void sgemm(
    const float* __restrict__ A, const float* __restrict__ A2,
    const float* __restrict__ B, const float* __restrict__ bias,
    float* __restrict__ C, int M, int N, int K)
{
    __shared__ float As[16][68];   // [k][m], pad->16B-aligned rows, 2-way max
    __shared__ float Bs[16][68];   // [k][n]

    const int tid = threadIdx.x;
    const int bm  = blockIdx.y * 64;
    const int bn  = blockIdx.x * 64;
    const int tx  = tid & 15;      // n-tile
    const int ty  = tid >> 4;      // m-tile

    // A-load: thread -> (m = tid>>2, k4 = (tid&3)*4)
    const int am = tid >> 2;
    const int ak = (tid & 3) * 4;
    // B-load: thread -> (k = tid>>4, n4 = (tid&15)*4)
    const int bk  = tid >> 4;
    const int bn4 = (tid & 15) * 4;

    float acc[4][4] = {};

    for (int k0 = 0; k0 < K; k0 += 16) {
        float4 a4 = make_float4(0.f, 0.f, 0.f, 0.f);
        const int arow = bm + am;
        if (arow < M) {
            a4 = *(const float4*)(A + (size_t)arow * K + k0 + ak);
            if (ADD2) {
                const float4 p4 = *(const float4*)(A2 + (size_t)arow * K + k0 + ak);
                a4.x += p4.x; a4.y += p4.y; a4.z += p4.z; a4.w += p4.w;
            }
        }
        As[ak + 0][am] = a4.x;
        As[ak + 1][am] = a4.y;
        As[ak + 2][am] = a4.z;
        As[ak + 3][am] = a4.w;

        const float4 b4 = *(const float4*)(B + (size_t)(k0 + bk) * N + bn + bn4);
        *(float4*)&Bs[bk][bn4] = b4;

        __syncthreads();

        #pragma unroll
        for (int k = 0; k < 16; ++k) {
            float a0 = As[k][ty * 4 + 0];
            float a1 = As[k][ty * 4 + 1];
            float a2 = As[k][ty * 4 + 2];
            float a3 = As[k][ty * 4 + 3];
            float b0 = Bs[k][tx * 4 + 0];
            float b1 = Bs[k][tx * 4 + 1];
            float b2 = Bs[k][tx * 4 + 2];
            float b3 = Bs[k][tx * 4 + 3];
            acc[0][0] += a0 * b0; acc[0][1] += a0 * b1; acc[0][2] += a0 * b2; acc[0][3] += a0 * b3;
            acc[1][0] += a1 * b0; acc[1][1] += a1 * b1; acc[1][2] += a1 * b2; acc[1][3] += a1 * b3;
            acc[2][0] += a2 * b0; acc[2][1] += a2 * b1; acc[2][2] += a2 * b2; acc[2][3] += a2 * b3;
            acc[3][0] += a3 * b0; acc[3][1] += a3 * b1; acc[3][2] += a3 * b2; acc[3][3] += a3 * b3;
        }
        __syncthreads();
    }

    #pragma unroll
    for (int i = 0; i < 4; ++i) {
        const int row = bm + ty * 4 + i;
        if (row >= M) continue;
        #pragma unroll
        for (int j = 0; j < 4; ++j) {
            const int col = bn + tx * 4 + j;
            float v = acc[i][j] + bias[col];
            if (RELU) v = fmaxf(v, 0.f);
            C[(size_t)row * N + col] = v;
        }
    }
}

// ---------------- deformable sampling ----------------
// one block per token; 256 threads = 8 heads x 32 channels
__global__ __launch_bounds__(256) void msda_sample(
    const float* __restrict__ value,  // [M, 256]
    const float* __restrict__ off,    // [M, 256]  (h,l,p,2)
    const float* __restrict__ attn,   // [M, 128]  (h, l*p) logits
    const float* __restrict__ refp,   // [M, 4, 2]
    float* __restrict__ out)          // [M, 256]
{
    const int row = blockIdx.x;
    const int n   = row / LEN_IN;
    const int tid = threadIdx.x;

    __shared__ float sw[8][16];   // softmax weights
    __shared__ float spx[8][16];  // sample x (pixel coords, grid_sample convention)
    __shared__ float spy[8][16];

    if (tid < 128) {
        const int h  = tid >> 4;
        const int lp = tid & 15;
        const int l  = lp >> 2;
        const int p  = lp & 3;
        const float ox = off[(size_t)row * 256 + h * 32 + l * 8 + p * 2 + 0];
        const float oy = off[(size_t)row * 256 + h * 32 + l * 8 + p * 2 + 1];
        const float rx = refp[((size_t)row * 4 + l) * 2 + 0];
        const float ry = refp[((size_t)row * 4 + l) * 2 + 1];
        const float W = (float)c_lvl_w[l];
        const float H = (float)c_lvl_h[l];
        const float locx = rx + ox / W;
        const float locy = ry + oy / H;
        spx[h][lp] = locx * W - 0.5f;
        spy[h][lp] = locy * H - 0.5f;
    } else if (tid < 136) {
        const int h = tid - 128;
        const float* ap = attn + (size_t)row * 128 + h * 16;
        float mx = -1e30f;
        float e[16];
        #pragma unroll
        for (int i = 0; i < 16; ++i) mx = fmaxf(mx, ap[i]);
        float s = 0.f;
        #pragma unroll
        for (int i = 0; i < 16; ++i) { e[i] = __expf(ap[i] - mx); s += e[i]; }
        const float inv = 1.f / s;
        #pragma unroll
        for (int i = 0; i < 16; ++i) sw[h][i] = e[i] * inv;
    }
    __syncthreads();

    const int h = tid >> 5;
    const int d = tid & 31;
    const int col = h * 32 + d;
    float acc = 0.f;

    #pragma unroll
    for (int l = 0; l < 4; ++l) {
        const int Hh = c_lvl_h[l];
        const int Ww = c_lvl_w[l];
        const int base = n * LEN_IN + c_lvl_s[l];
        #pragma unroll
        for (int p = 0; p < 4; ++p) {
            const int lp = l * 4 + p;
            const float x  = spx[h][lp];
            const float y  = spy[h][lp];
            const float wt = sw[h][lp];
            const float xf = floorf(x);
            const float yf = floorf(y);
            const float fx = x - xf;
            const float fy = y - yf;
            const int x0 = (int)xf, y0 = (int)yf;
            const int x1 = x0 + 1,  y1 = y0 + 1;
            const bool vx0 = (x0 >= 0) & (x0 < Ww);
            const bool vx1 = (x1 >= 0) & (x1 < Ww);
            const bool vy0 = (y0 >= 0) & (y0 < Hh);
            const bool vy1 = (y1 >= 0) & (y1 < Hh);
            const int cx0 = min(max(x0, 0), Ww - 1);
            const int cx1 = min(max(x1, 0), Ww - 1);
            const int cy0 = min(max(y0, 0), Hh - 1);
            const int cy1 = min(max(y1, 0), Hh - 1);
            const float w00 = (1.f - fx) * (1.f - fy);
            const float w01 = fx * (1.f - fy);
            const float w10 = (1.f - fx) * fy;
            const float w11 = fx * fy;
            float s00 = 0.f, s01 = 0.f, s10 = 0.f, s11 = 0.f;
            if (vx0 && vy0) s00 = value[(size_t)(base + cy0 * Ww + cx0) * 256 + col];
            if (vx1 && vy0) s01 = value[(size_t)(base + cy0 * Ww + cx1) * 256 + col];
            if (vx0 && vy1) s10 = value[(size_t)(base + cy1 * Ww + cx0) * 256 + col];
            if (vx1 && vy1) s11 = value[(size_t)(base + cy1 * Ww + cx1) * 256 + col];
            acc += wt * (w00 * s00 + w01 * s01 + w10 * s10 + w11 * s11);
        }
    }
    out[(size_t)row * 256 + tid] = acc;
}

// ---------------- residual + LayerNorm ----------------
// out = LN(a + b) * g + be ; one block (256 thr) per row
__global__ __launch_bounds__(256) void add_ln(
    const float* __restrict__ a, const float* __restrict__ b,
    const float* __restrict__ g, const float* __restrict__ be,
    float* __restrict__ out)
{
    const int row = blockIdx.x;
    const int tid = threadIdx.x;
    const float v = a[(size_t)row * 256 + tid] + b[(size_t)row * 256 + tid];

    float s = v, s2 = v * v;
    #pragma unroll
    for (int o = 32; o > 0; o >>= 1) {
        s  += __shfl_down(s, o);
        s2 += __shfl_down(s2, o);
    }
    __shared__ float ss[4], ss2[4];
    const int wid = tid >> 6, lane = tid & 63;
    if (lane == 0) { ss[wid] = s; ss2[wid] = s2; }
    __syncthreads();
    if (tid == 0) {
        const float t  = ss[0] + ss[1] + ss[2] + ss[3];
        const float t2 = ss2[0] + ss2[1] + ss2[2] + ss2[3];
        const float mu = t * (1.f / 256.f);
        const float var = t2 * (1.f / 256.f) - mu * mu;
        ss[0]  = mu;
        ss2[0] = rsqrtf(var + 1e-5f);
    }
    __syncthreads();
    const float mu = ss[0], rs = ss2[0];
    out[(size_t)row * 256 + tid] = (v - mu) * rs * g[tid] + be[tid];
}

// ---------------- launch ----------------
extern "C" void kernel_launch(void* const* d_in, const int* in_sizes, int n_in,
                              void* d_out, int out_size, void* d_ws, size_t ws_size,
                              hipStream_t stream)
{
    const float* src     = (const float*)d_in[0];
    const float* pos     = (const float*)d_in[1];
    const float* refp    = (const float*)d_in[2];
    // d_in[3] spatial_shapes, d_in[4] level_start_index : static, hardcoded
    const float* W_value = (const float*)d_in[5];
    const float* b_value = (const float*)d_in[6];
    const float* W_off   = (const float*)d_in[7];
    const float* b_off   = (const float*)d_in[8];
    const float* W_attn  = (const float*)d_in[9];
    const float* b_attn  = (const float*)d_in[10];
    const float* W_out   = (const float*)d_in[11];
    const float* b_out   = (const float*)d_in[12];
    const float* W1      = (const float*)d_in[13];
    const float* b1      = (const float*)d_in[14];
    const float* W2      = (const float*)d_in[15];
    const float* b2      = (const float*)d_in[16];
    const float* g1      = (const float*)d_in[17];
    const float* be1     = (const float*)d_in[18];
    const float* g2      = (const float*)d_in[19];
    const float* be2     = (const float*)d_in[20];
    float* outp = (float*)d_out;

    const int M = M_TOK;
    char* ws = (char*)d_ws;
    // layout (floats): [0, 256M) value | [256M, 512M) off | [512M, 640M) attn
    // [640M, 896M) sampled | [896M,1152M) src2 | [1152M,1408M) x | [1408M,1664M) f2
    // hbuf reuses [0, 1024M) after the front-end is dead.
    float* value = (float*)ws;
    float* off   = (float*)(ws + (size_t)M * 256 * 4);
    float* attn  = (float*)(ws + (size_t)M * 512 * 4);
    float* outs  = (float*)(ws + (size_t)M * 640 * 4);
    float* src2  = (float*)(ws + (size_t)M * 896 * 4);
    float* x     = (float*)(ws + (size_t)M * 1152 * 4);
    float* f2    = (float*)(ws + (size_t)M * 1408 * 4);
    float* hbuf  = (float*)ws;   // [M,1024] overlaps value..src2 (dead by FFN1)

    const dim3 blk(256);
    const int gm = (M + 63) / 64;

    // value = src @ W_value + b_value
    sgemm<false, false><<<dim3(256 / 64, gm), blk, 0, stream>>>(src, nullptr, W_value, b_value, value, M, 256, 256);
    // off = (src+pos) @ W_off + b_off
    sgemm<true, false><<<dim3(256 / 64, gm), blk, 0, stream>>>(src, pos, W_off, b_off, off, M, 256, 256);
    // attn = (src+pos) @ W_attn + b_attn
    sgemm<true, false><<<dim3(128 / 64, gm), blk, 0, stream>>>(src, pos, W_attn, b_attn, attn, M, 128, 256);
    // deformable attention sampling
    msda_sample<<<dim3(M), blk, 0, stream>>>(value, off, attn, refp, outs);
    // src2 = sampled @ W_out + b_out
    sgemm<false, false><<<dim3(256 / 64, gm), blk, 0, stream>>>(outs, nullptr, W_out, b_out, src2, M, 256, 256);
    // x = LN(src + src2)
    add_ln<<<dim3(M), blk, 0, stream>>>(src, src2, g1, be1, x);
    // hbuf = relu(x @ W1 + b1)
    sgemm<false, true><<<dim3(1024 / 64, gm), blk, 0, stream>>>(x, nullptr, W1, b1, hbuf, M, 1024, 256);
    // f2 = hbuf @ W2 + b2
    sgemm<false, false><<<dim3(256 / 64, gm), blk, 0, stream>>>(hbuf, nullptr, W2, b2, f2, M, 256, 1024);
    // out = LN(x + f2)
    add_ln<<<dim3(M), blk, 0, stream>>>(x, f2, g2, be2, outp);
}

// Round 2
// 419.750 us; speedup vs baseline: 2.2573x; 2.2573x over previous
//
#include <hip/hip_runtime.h>
#include <hip/hip_bf16.h>
#include <cstdint>

// ---------------- static problem config ----------------
#define D_MODEL   256
#define N_HEADS   8
#define N_LEVELS  4
#define N_POINTS  4
#define D_FFN     1024
#define D_HEAD    32
#define LEN_IN    13294          // 100*100 + 50*50 + 25*25 + 13*13
#define NBATCH    2
#define M_TOK     (NBATCH * LEN_IN)   // 26588
#define M_PAD     26624               // 208 * 128

__constant__ int c_lvl_h[4] = {100, 50, 25, 13};
__constant__ int c_lvl_w[4] = {100, 50, 25, 13};
__constant__ int c_lvl_s[4] = {0, 10000, 12500, 13125};

typedef __attribute__((ext_vector_type(8))) __bf16 bf16x8;
typedef __attribute__((ext_vector_type(4))) __bf16 bf16x4;
typedef __attribute__((ext_vector_type(4))) float  f32x4;

// async global->LDS, 16B per lane; lds base must be wave-uniform (lane i lands at base + i*16)
__device__ __forceinline__ void lds_direct16(const void* g, void* l) {
    __builtin_amdgcn_global_load_lds(
        (const __attribute__((address_space(1))) uint32_t*)(uintptr_t)g,
        (__attribute__((address_space(3))) uint32_t*)(uintptr_t)l,
        16, 0, 0);
}

// ---------------- fp32 -> bf16 conversions ----------------
__global__ __launch_bounds__(256) void cvt_src_q(
    const float4* __restrict__ src, const float4* __restrict__ pos,
    bf16x4* __restrict__ sb, bf16x4* __restrict__ qb, int n4)
{
    const int i = blockIdx.x * 256 + threadIdx.x;
    if (i >= n4) return;
    const float4 s = src[i];
    const float4 p = pos[i];
    bf16x4 sv = { (__bf16)s.x, (__bf16)s.y, (__bf16)s.z, (__bf16)s.w };
    bf16x4 qv = { (__bf16)(s.x + p.x), (__bf16)(s.y + p.y),
                  (__bf16)(s.z + p.z), (__bf16)(s.w + p.w) };
    sb[i] = sv;
    qb[i] = qv;
}

// Wt[n][k] = (bf16) W[k][n] ; grid (N/32, K/32), block (32,8)
__global__ __launch_bounds__(256) void transpose_cvt(
    const float* __restrict__ W, __bf16* __restrict__ Wt, int K, int N)
{
    __shared__ float t[32][33];
    const int tx = threadIdx.x;
    const int ty = threadIdx.y;
    const int n0 = blockIdx.x * 32;
    const int k0 = blockIdx.y * 32;
    #pragma unroll
    for (int j = 0; j < 4; ++j)
        t[ty + j * 8][tx] = W[(size_t)(k0 + ty + j * 8) * N + n0 + tx];
    __syncthreads();
    #pragma unroll
    for (int j = 0; j < 4; ++j)
        Wt[(size_t)(n0 + ty + j * 8) * K + k0 + tx] = (__bf16)t[tx][ty + j * 8];
}

// ---------------- bf16 MFMA GEMM (m97 structure) ----------------
// C[M,N] = act(A @ Bt^T + bias); A [Mpad,K] bf16 row-major, Bt [N,K] bf16 row-major.
// 128x128 tile, BK=32, 256 thr = 4 waves (2x2), each wave 4x4 of 16x16x32 MFMA.
template <typename OutT, bool RELU>
__global__ __launch_bounds__(256) void gemm_mfma(
    const __bf16* __restrict__ A, const __bf16* __restrict__ Bt,
    const float* __restrict__ bias, OutT* __restrict__ C,
    int M, int N, int K)
{
    __shared__ __bf16 As[128 * 32];
    __shared__ __bf16 Bs[128 * 32];

    const int tid  = threadIdx.x;
    const int lane = tid & 63;
    const int wv   = tid >> 6;
    const int bm   = blockIdx.y * 128;
    const int bn   = blockIdx.x * 128;
    const int wm   = (wv >> 1) * 64;
    const int wn   = (wv & 1) * 64;
    const int srow = lane >> 2;        // staging row within 16-row chunk
    const int skc  = (lane & 3) * 8;   // staging k-chunk (elems)
    const int fm   = lane & 15;        // fragment row/col
    const int fko  = (lane >> 4) * 8;  // fragment k offset

    f32x4 acc[4][4] = {};

    for (int k0 = 0; k0 < K; k0 += 32) {
        #pragma unroll
        for (int c = 0; c < 2; ++c) {
            const int r = wv * 32 + c * 16;
            lds_direct16(A  + (size_t)(bm + r + srow) * K + k0 + skc, As + r * 32);
            lds_direct16(Bt + (size_t)(bn + r + srow) * K + k0 + skc, Bs + r * 32);
        }
        __syncthreads();

        bf16x8 af[4], bfr[4];
        #pragma unroll
        for (int t = 0; t < 4; ++t) {
            af[t]  = *(const bf16x8*)(As + (wm + t * 16 + fm) * 32 + fko);
            bfr[t] = *(const bf16x8*)(Bs + (wn + t * 16 + fm) * 32 + fko);
        }
        #pragma unroll
        for (int mt = 0; mt < 4; ++mt)
            #pragma unroll
            for (int nt = 0; nt < 4; ++nt)
                acc[mt][nt] = __builtin_amdgcn_mfma_f32_16x16x32_bf16(
                    af[mt], bfr[nt], acc[mt][nt], 0, 0, 0);
        __syncthreads();
    }

    // C/D layout: col = lane&15, row = (lane>>4)*4 + reg  [m89-verified]
    const int ecol = lane & 15;
    const int erow = (lane >> 4) * 4;
    #pragma unroll
    for (int nt = 0; nt < 4; ++nt) {
        const int col = bn + wn + nt * 16 + ecol;
        const float bv = bias[col];
        #pragma unroll
        for (int mt = 0; mt < 4; ++mt) {
            #pragma unroll
            for (int r = 0; r < 4; ++r) {
                const int row = bm + wm + mt * 16 + erow + r;
                if (row < M) {
                    float v = acc[mt][nt][r] + bv;
                    if (RELU) v = fmaxf(v, 0.f);
                    C[(size_t)row * N + col] = (OutT)v;
                }
            }
        }
    }
}

// ---------------- deformable sampling ----------------
// one block per token; setup by 136 threads -> LDS; gather by 256 thr = 8 heads x 32 ch
__global__ __launch_bounds__(256) void msda_sample(
    const __bf16* __restrict__ value, // [Mpad, 256] bf16
    const float* __restrict__ off,    // [M, 256]  (h,l,p,2)
    const float* __restrict__ attn,   // [M, 128]  (h, l*p) logits
    const float* __restrict__ refp,   // [M, 4, 2]
    __bf16* __restrict__ out)         // [Mpad, 256] bf16 (rows < M written)
{
    const int row = blockIdx.x;
    const int n   = row / LEN_IN;
    const int tid = threadIdx.x;

    __shared__ int   sidx[8][16][4];  // value element offset (already *256), 0 if invalid
    __shared__ float swt [8][16][4];  // bilinear corner weight (later * softmax weight)
    __shared__ float sw  [8][16];     // softmax weights

    if (tid < 128) {
        const int h  = tid >> 4;
        const int lp = tid & 15;
        const int l  = lp >> 2;
        const int p  = lp & 3;
        const float ox = off[(size_t)row * 256 + h * 32 + l * 8 + p * 2 + 0];
        const float oy = off[(size_t)row * 256 + h * 32 + l * 8 + p * 2 + 1];
        const float rx = refp[((size_t)row * 4 + l) * 2 + 0];
        const float ry = refp[((size_t)row * 4 + l) * 2 + 1];
        const int Ww = c_lvl_w[l];
        const int Hh = c_lvl_h[l];
        const float x = (rx + ox / (float)Ww) * (float)Ww - 0.5f;
        const float y = (ry + oy / (float)Hh) * (float)Hh - 0.5f;
        const float xf = floorf(x), yf = floorf(y);
        const float fx = x - xf,    fy = y - yf;
        const int x0 = (int)xf, y0 = (int)yf;
        const int base = n * LEN_IN + c_lvl_s[l];
        #pragma unroll
        for (int c = 0; c < 4; ++c) {
            const int dx = c & 1, dy = c >> 1;
            const int xi = x0 + dx, yi = y0 + dy;
            const bool valid = (xi >= 0) & (xi < Ww) & (yi >= 0) & (yi < Hh);
            const float w = (dx ? fx : 1.f - fx) * (dy ? fy : 1.f - fy);
            sidx[h][lp][c] = valid ? (base + yi * Ww + xi) * 256 : 0;
            swt [h][lp][c] = valid ? w : 0.f;
        }
    } else if (tid < 136) {
        const int h = tid - 128;
        const float* ap = attn + (size_t)row * 128 + h * 16;
        float mx = -1e30f;
        float e[16];
        #pragma unroll
        for (int i = 0; i < 16; ++i) mx = fmaxf(mx, ap[i]);
        float s = 0.f;
        #pragma unroll
        for (int i = 0; i < 16; ++i) { e[i] = __expf(ap[i] - mx); s += e[i]; }
        const float inv = 1.f / s;
        #pragma unroll
        for (int i = 0; i < 16; ++i) sw[h][i] = e[i] * inv;
    }
    __syncthreads();
    if (tid < 128) {
        const int h = tid >> 4, lp = tid & 15;
        const float a = sw[h][lp];
        #pragma unroll
        for (int c = 0; c < 4; ++c) swt[h][lp][c] *= a;
    }
    __syncthreads();

    const int h = tid >> 5;
    const int col = tid;          // h*32 + d == tid
    float acc = 0.f;
    #pragma unroll
    for (int lp = 0; lp < 16; ++lp) {
        #pragma unroll
        for (int c = 0; c < 4; ++c) {
            acc += swt[h][lp][c] * (float)value[sidx[h][lp][c] + col];
        }
    }
    out[(size_t)row * 256 + tid] = (__bf16)acc;
}

// ---------------- residual + LayerNorm ----------------
template <bool BF16OUT>
__global__ __launch_bounds__(256) void add_ln(
    const float* __restrict__ a, const float* __restrict__ b,
    const float* __restrict__ g, const float* __restrict__ be,
    float* __restrict__ out, __bf16* __restrict__ outb)
{
    const int row = blockIdx.x;
    const int tid = threadIdx.x;
    const float v = a[(size_t)row * 256 + tid] + b[(size_t)row * 256 + tid];

    float s = v, s2 = v * v;
    #pragma unroll
    for (int o = 32; o > 0; o >>= 1) {
        s  += __shfl_down(s, o);
        s2 += __shfl_down(s2, o);
    }
    __shared__ float ss[4], ss2[4];
    const int wid = tid >> 6, lane = tid & 63;
    if (lane == 0) { ss[wid] = s; ss2[wid] = s2; }
    __syncthreads();
    if (tid == 0) {
        const float t  = ss[0] + ss[1] + ss[2] + ss[3];
        const float t2 = ss2[0] + ss2[1] + ss2[2] + ss2[3];
        const float mu = t * (1.f / 256.f);
        const float var = t2 * (1.f / 256.f) - mu * mu;
        ss[0]  = mu;
        ss2[0] = rsqrtf(var + 1e-5f);
    }
    __syncthreads();
    const float mu = ss[0], rs = ss2[0];
    const float o = (v - mu) * rs * g[tid] + be[tid];
    out[(size_t)row * 256 + tid] = o;
    if (BF16OUT) outb[(size_t)row * 256 + tid] = (__bf16)o;
}

// ---------------- launch ----------------
extern "C" void kernel_launch(void* const* d_in, const int* in_sizes, int n_in,
                              void* d_out, int out_size, void* d_ws, size_t ws_size,
                              hipStream_t stream)
{
    const float* src     = (const float*)d_in[0];
    const float* pos     = (const float*)d_in[1];
    const float* refp    = (const float*)d_in[2];
    const float* W_value = (const float*)d_in[5];
    const float* b_value = (const float*)d_in[6];
    const float* W_off   = (const float*)d_in[7];
    const float* b_off   = (const float*)d_in[8];
    const float* W_attn  = (const float*)d_in[9];
    const float* b_attn  = (const float*)d_in[10];
    const float* W_out   = (const float*)d_in[11];
    const float* b_out   = (const float*)d_in[12];
    const float* W1      = (const float*)d_in[13];
    const float* b1      = (const float*)d_in[14];
    const float* W2      = (const float*)d_in[15];
    const float* b2      = (const float*)d_in[16];
    const float* g1      = (const float*)d_in[17];
    const float* be1     = (const float*)d_in[18];
    const float* g2      = (const float*)d_in[19];
    const float* be2     = (const float*)d_in[20];
    float* outp = (float*)d_out;

    const int M = M_TOK;
    char* ws = (char*)d_ws;
    const size_t R2 = (size_t)M_PAD * 256 * 2;   // 13,631,488 B

    __bf16* src_b = (__bf16*)(ws);
    __bf16* q_b   = (__bf16*)(ws + R2);
    __bf16* val_b = (__bf16*)(ws + 2 * R2);
    float*  off   = (float*)(ws + 3 * R2);       // 2*R2
    float*  attn  = (float*)(ws + 5 * R2);       // R2
    __bf16* samp  = (__bf16*)(ws + 6 * R2);
    float*  src2  = (float*)(ws + 7 * R2);       // 2*R2
    float*  x     = (float*)(ws + 9 * R2);       // 2*R2
    __bf16* x_b   = (__bf16*)(ws + 11 * R2);
    float*  f2    = (float*)(ws + 7 * R2);       // overlay src2 (dead after LN1)
    __bf16* hbuf  = (__bf16*)(ws);               // overlay [0,4*R2) (dead after sample)
    __bf16* wbase = (__bf16*)(ws + 12 * R2);
    __bf16* Wt_value = wbase;                    // [256][256]
    __bf16* Wt_off   = wbase + 65536;            // [256][256]
    __bf16* Wt_attn  = wbase + 131072;           // [128][256]
    __bf16* Wt_out   = wbase + 163840;           // [256][256]
    __bf16* Wt1      = wbase + 229376;           // [1024][256]
    __bf16* Wt2      = wbase + 491520;           // [256][1024]

    const dim3 blk(256);
    const dim3 tblk(32, 8);
    const int n4 = M * 256 / 4;

    cvt_src_q<<<dim3((n4 + 255) / 256), blk, 0, stream>>>(
        (const float4*)src, (const float4*)pos, (bf16x4*)src_b, (bf16x4*)q_b, n4);
    transpose_cvt<<<dim3(8, 8),  tblk, 0, stream>>>(W_value, Wt_value, 256, 256);
    transpose_cvt<<<dim3(8, 8),  tblk, 0, stream>>>(W_off,   Wt_off,   256, 256);
    transpose_cvt<<<dim3(4, 8),  tblk, 0, stream>>>(W_attn,  Wt_attn,  256, 128);
    transpose_cvt<<<dim3(8, 8),  tblk, 0, stream>>>(W_out,   Wt_out,   256, 256);
    transpose_cvt<<<dim3(32, 8), tblk, 0, stream>>>(W1,      Wt1,      256, 1024);
    transpose_cvt<<<dim3(8, 32), tblk, 0, stream>>>(W2,      Wt2,      1024, 256);

    const int gm = M_PAD / 128;  // 208

    gemm_mfma<__bf16, false><<<dim3(2, gm), blk, 0, stream>>>(src_b, Wt_value, b_value, val_b, M, 256, 256);
    gemm_mfma<float,  false><<<dim3(2, gm), blk, 0, stream>>>(q_b,   Wt_off,   b_off,   off,   M, 256, 256);
    gemm_mfma<float,  false><<<dim3(1, gm), blk, 0, stream>>>(q_b,   Wt_attn,  b_attn,  attn,  M, 128, 256);

    msda_sample<<<dim3(M), blk, 0, stream>>>(val_b, off, attn, refp, samp);

    gemm_mfma<float,  false><<<dim3(2, gm), blk, 0, stream>>>(samp, Wt_out, b_out, src2, M, 256, 256);
    add_ln<true><<<dim3(M), blk, 0, stream>>>(src, src2, g1, be1, x, x_b);
    gemm_mfma<__bf16, true ><<<dim3(8, gm), blk, 0, stream>>>(x_b,  Wt1, b1, hbuf, M, 1024, 256);
    gemm_mfma<float,  false><<<dim3(2, gm), blk, 0, stream>>>(hbuf, Wt2, b2, f2,   M, 256, 1024);
    add_ln<false><<<dim3(M), blk, 0, stream>>>(x, f2, g2, be2, outp, nullptr);
}

// Round 3
// 404.971 us; speedup vs baseline: 2.3397x; 1.0365x over previous
//
#include <hip/hip_runtime.h>
#include <hip/hip_bf16.h>
#include <cstdint>

// ---------------- static problem config ----------------
#define D_MODEL   256
#define N_HEADS   8
#define N_LEVELS  4
#define N_POINTS  4
#define D_FFN     1024
#define D_HEAD    32
#define LEN_IN    13294          // 100*100 + 50*50 + 25*25 + 13*13
#define NBATCH    2
#define M_TOK     (NBATCH * LEN_IN)   // 26588
#define M_PAD     26624               // 208 * 128

__constant__ int c_lvl_h[4] = {100, 50, 25, 13};
__constant__ int c_lvl_w[4] = {100, 50, 25, 13};
__constant__ int c_lvl_s[4] = {0, 10000, 12500, 13125};

typedef __attribute__((ext_vector_type(8))) __bf16 bf16x8;
typedef __attribute__((ext_vector_type(4))) __bf16 bf16x4;
typedef __attribute__((ext_vector_type(2))) __bf16 bf16x2;
typedef __attribute__((ext_vector_type(4))) float  f32x4;

__device__ __forceinline__ float bflo(uint32_t w) { return __uint_as_float(w << 16); }
__device__ __forceinline__ float bfhi(uint32_t w) { return __uint_as_float(w & 0xffff0000u); }

// async global->LDS, 16B per lane; lds base wave-uniform (lane i lands at base + i*16)
__device__ __forceinline__ void lds_direct16(const void* g, void* l) {
    __builtin_amdgcn_global_load_lds(
        (const __attribute__((address_space(1))) uint32_t*)(uintptr_t)g,
        (__attribute__((address_space(3))) uint32_t*)(uintptr_t)l,
        16, 0, 0);
}

// ---------------- fp32 -> bf16 conversions ----------------
__global__ __launch_bounds__(256) void cvt_src_q(
    const float4* __restrict__ src, const float4* __restrict__ pos,
    bf16x4* __restrict__ sb, bf16x4* __restrict__ qb, int n4)
{
    const int i = blockIdx.x * 256 + threadIdx.x;
    if (i >= n4) return;
    const float4 s = src[i];
    const float4 p = pos[i];
    bf16x4 sv = { (__bf16)s.x, (__bf16)s.y, (__bf16)s.z, (__bf16)s.w };
    bf16x4 qv = { (__bf16)(s.x + p.x), (__bf16)(s.y + p.y),
                  (__bf16)(s.z + p.z), (__bf16)(s.w + p.w) };
    sb[i] = sv;
    qb[i] = qv;
}

// ---------------- all weight transposes + bias concat in ONE dispatch ----------------
// Wt[n][k] = (bf16) W[k][n]; descriptors hardcoded. block (32,8). grid 737.
__global__ __launch_bounds__(256) void transpose_all(
    const float* __restrict__ s0, const float* __restrict__ s1, const float* __restrict__ s2,
    const float* __restrict__ s3, const float* __restrict__ s4, const float* __restrict__ s5,
    __bf16* __restrict__ d0, __bf16* __restrict__ d1, __bf16* __restrict__ d2,
    __bf16* __restrict__ d3, __bf16* __restrict__ d4, __bf16* __restrict__ d5,
    const float* __restrict__ b_off, const float* __restrict__ b_attn,
    float* __restrict__ bias_oa)
{
    const int tx = threadIdx.x;
    const int ty = threadIdx.y;
    const int tid = ty * 32 + tx;
    const int b = blockIdx.x;
    if (b == 736) {   // bias concat: [b_off(256) | b_attn(128)]
        if (tid < 256) bias_oa[tid] = b_off[tid];
        if (tid < 128) bias_oa[256 + tid] = b_attn[tid];
        return;
    }
    const int starts[7] = {0, 64, 128, 160, 224, 480, 736};
    const int Ks[6] = {256, 256, 256, 256, 256, 1024};
    const int Ns[6] = {256, 256, 128, 256, 1024, 256};
    const float* srcs[6] = {s0, s1, s2, s3, s4, s5};
    __bf16* dsts[6] = {d0, d1, d2, d3, d4, d5};
    int i = 0;
    while (b >= starts[i + 1]) ++i;
    const int t = b - starts[i];
    const int K = Ks[i], N = Ns[i];
    const float* W = srcs[i];
    __bf16* Wt = dsts[i];
    const int ntx = N >> 5;
    const int n0 = (t % ntx) * 32;
    const int k0 = (t / ntx) * 32;

    __shared__ float tl[32][33];
    #pragma unroll
    for (int j = 0; j < 4; ++j)
        tl[ty + j * 8][tx] = W[(size_t)(k0 + ty + j * 8) * N + n0 + tx];
    __syncthreads();
    #pragma unroll
    for (int j = 0; j < 4; ++j)
        Wt[(size_t)(n0 + ty + j * 8) * K + k0 + tx] = (__bf16)tl[tx][ty + j * 8];
}

// ---------------- bf16 MFMA GEMM (m97 structure, NP k-panels per barrier) ----------------
// C[M,N] = act(A @ Bt^T + bias); A [Mpad,K] bf16 row-major, Bt [N,K] bf16 row-major.
// 128x128 tile, 256 thr = 4 waves (2x2), each wave 4x4 of 16x16x32 MFMA.
template <typename OutT, bool RELU, int NP>
__global__ __launch_bounds__(256) void gemm_mfma(
    const __bf16* __restrict__ A, const __bf16* __restrict__ Bt,
    const float* __restrict__ bias, OutT* __restrict__ C,
    int M, int N, int K)
{
    __shared__ __bf16 As[NP * 128 * 32];
    __shared__ __bf16 Bs[NP * 128 * 32];

    const int tid  = threadIdx.x;
    const int lane = tid & 63;
    const int wv   = tid >> 6;
    const int bm   = blockIdx.y * 128;
    const int bn   = blockIdx.x * 128;
    const int wm   = (wv >> 1) * 64;
    const int wn   = (wv & 1) * 64;
    const int srow = lane >> 2;        // staging row within 16-row chunk
    const int skc  = (lane & 3) * 8;   // staging k-chunk (elems)
    const int fm   = lane & 15;        // fragment row/col
    const int fko  = (lane >> 4) * 8;  // fragment k offset

    f32x4 acc[4][4] = {};

    for (int k0 = 0; k0 < K; k0 += 32 * NP) {
        #pragma unroll
        for (int p = 0; p < NP; ++p) {
            #pragma unroll
            for (int c = 0; c < 2; ++c) {
                const int r = wv * 32 + c * 16;
                lds_direct16(A  + (size_t)(bm + r + srow) * K + k0 + p * 32 + skc, As + p * 4096 + r * 32);
                lds_direct16(Bt + (size_t)(bn + r + srow) * K + k0 + p * 32 + skc, Bs + p * 4096 + r * 32);
            }
        }
        __syncthreads();

        #pragma unroll
        for (int p = 0; p < NP; ++p) {
            bf16x8 af[4], bfr[4];
            #pragma unroll
            for (int t = 0; t < 4; ++t) {
                af[t]  = *(const bf16x8*)(As + p * 4096 + (wm + t * 16 + fm) * 32 + fko);
                bfr[t] = *(const bf16x8*)(Bs + p * 4096 + (wn + t * 16 + fm) * 32 + fko);
            }
            #pragma unroll
            for (int mt = 0; mt < 4; ++mt)
                #pragma unroll
                for (int nt = 0; nt < 4; ++nt)
                    acc[mt][nt] = __builtin_amdgcn_mfma_f32_16x16x32_bf16(
                        af[mt], bfr[nt], acc[mt][nt], 0, 0, 0);
        }
        __syncthreads();
    }

    // C/D layout: col = lane&15, row = (lane>>4)*4 + reg  [m89-verified]
    const int ecol = lane & 15;
    const int erow = (lane >> 4) * 4;
    #pragma unroll
    for (int nt = 0; nt < 4; ++nt) {
        const int col = bn + wn + nt * 16 + ecol;
        const float bv = bias[col];
        #pragma unroll
        for (int mt = 0; mt < 4; ++mt) {
            #pragma unroll
            for (int r = 0; r < 4; ++r) {
                const int row = bm + wm + mt * 16 + erow + r;
                if (row < M) {
                    float v = acc[mt][nt][r] + bv;
                    if (RELU) v = fmaxf(v, 0.f);
                    C[(size_t)row * N + col] = (OutT)v;
                }
            }
        }
    }
}

// ---------------- deformable sampling ----------------
// 2 tokens per block; 128 thr/token = 8 heads x 16 channel-pairs, bf16x2 gathers.
struct alignas(8) IW { int idx; float wt; };

__global__ __launch_bounds__(256) void msda_sample(
    const __bf16* __restrict__ value, // [Mpad, 256] bf16
    const __bf16* __restrict__ oa,    // [Mpad, 384] bf16: [off(256) | attn(128)]
    const float* __restrict__ refp,   // [M, 4, 2]
    __bf16* __restrict__ out)         // [Mpad, 256] bf16
{
    __shared__ IW   sc[2][8][17][4];  // [token][head][lp(+pad)][corner]; pad->bank shift 8/head
    __shared__ float sw[2][8][16];    // softmax weights

    const int tid = threadIdx.x;
    const int tt  = tid >> 7;         // token within pair
    const int u   = tid & 127;
    const int row = blockIdx.x * 2 + tt;
    const int h   = u >> 4;
    const int lp  = u & 15;

    // phase 1a (all 256 threads): corner idx + bilinear weights
    {
        const int l  = lp >> 2;
        const int Ww = c_lvl_w[l];
        const int Hh = c_lvl_h[l];
        const uint32_t opk = *(const uint32_t*)(oa + (size_t)row * 384 + h * 32 + lp * 2);
        const float ox = bflo(opk), oy = bfhi(opk);
        const float rx = refp[((size_t)row * 4 + l) * 2 + 0];
        const float ry = refp[((size_t)row * 4 + l) * 2 + 1];
        const float x = (rx + ox / (float)Ww) * (float)Ww - 0.5f;
        const float y = (ry + oy / (float)Hh) * (float)Hh - 0.5f;
        const float xf = floorf(x), yf = floorf(y);
        const float fx = x - xf,    fy = y - yf;
        const int x0 = (int)xf, y0 = (int)yf;
        const int n  = row / LEN_IN;
        const int base = n * LEN_IN + c_lvl_s[l];
        #pragma unroll
        for (int c = 0; c < 4; ++c) {
            const int dx = c & 1, dy = c >> 1;
            const int xi = x0 + dx, yi = y0 + dy;
            const bool valid = (xi >= 0) & (xi < Ww) & (yi >= 0) & (yi < Hh);
            sc[tt][h][lp][c].idx = valid ? (base + yi * Ww + xi) * 256 : 0;
            sc[tt][h][lp][c].wt  = valid ? (dx ? fx : 1.f - fx) * (dy ? fy : 1.f - fy) : 0.f;
        }
    }
    // phase 1b (16 threads, concurrent with 1a): per-(token,head) softmax of 16 logits
    if (tid < 16) {
        const int t2 = tid >> 3, h2 = tid & 7;
        const int r2 = blockIdx.x * 2 + t2;
        const __bf16* ap = oa + (size_t)r2 * 384 + 256 + h2 * 16;
        float e[16], mx = -1e30f;
        #pragma unroll
        for (int i = 0; i < 16; ++i) { e[i] = (float)ap[i]; mx = fmaxf(mx, e[i]); }
        float s = 0.f;
        #pragma unroll
        for (int i = 0; i < 16; ++i) { e[i] = __expf(e[i] - mx); s += e[i]; }
        const float inv = 1.f / s;
        #pragma unroll
        for (int i = 0; i < 16; ++i) sw[t2][h2][i] = e[i] * inv;
    }
    __syncthreads();
    // phase 2: fold softmax weight into corner weights
    {
        const float a = sw[tt][h][lp];
        #pragma unroll
        for (int c = 0; c < 4; ++c) sc[tt][h][lp][c].wt *= a;
    }
    __syncthreads();

    // phase 3: gather. thread handles channels (h*32 + 2*lp, +1)
    const uint32_t coff = (uint32_t)(h * 32 + lp * 2) * 2;  // byte offset within row
    const char* vb = (const char*)value + coff;
    float ax = 0.f, ay = 0.f;
    #pragma unroll
    for (int q = 0; q < 16; ++q) {
        #pragma unroll
        for (int c = 0; c < 4; ++c) {
            const IW s = sc[tt][h][q][c];
            const uint32_t w2 = *(const uint32_t*)(vb + (uint32_t)s.idx * 2u);
            ax += s.wt * bflo(w2);
            ay += s.wt * bfhi(w2);
        }
    }
    bf16x2 o = { (__bf16)ax, (__bf16)ay };
    *(bf16x2*)((char*)out + (size_t)row * 512 + coff) = o;
}

// ---------------- residual + LayerNorm (wave per row, float4) ----------------
template <bool BF16OUT>
__global__ __launch_bounds__(256) void add_ln(
    const float4* __restrict__ a, const float4* __restrict__ b,
    const float4* __restrict__ g4, const float4* __restrict__ be4,
    float4* __restrict__ out, bf16x4* __restrict__ outb)
{
    const int tid  = threadIdx.x;
    const int row  = blockIdx.x * 4 + (tid >> 6);
    const int lane = tid & 63;
    const size_t e = (size_t)row * 64 + lane;
    const float4 va = a[e];
    const float4 vb = b[e];
    float4 v = { va.x + vb.x, va.y + vb.y, va.z + vb.z, va.w + vb.w };

    float s  = v.x + v.y + v.z + v.w;
    float s2 = v.x * v.x + v.y * v.y + v.z * v.z + v.w * v.w;
    #pragma unroll
    for (int o = 32; o > 0; o >>= 1) {
        s  += __shfl_down(s, o);
        s2 += __shfl_down(s2, o);
    }
    s  = __shfl(s, 0);
    s2 = __shfl(s2, 0);
    const float mu  = s * (1.f / 256.f);
    const float var = s2 * (1.f / 256.f) - mu * mu;
    const float rs  = rsqrtf(var + 1e-5f);
    const float4 g = g4[lane];
    const float4 be = be4[lane];
    float4 o;
    o.x = (v.x - mu) * rs * g.x + be.x;
    o.y = (v.y - mu) * rs * g.y + be.y;
    o.z = (v.z - mu) * rs * g.z + be.z;
    o.w = (v.w - mu) * rs * g.w + be.w;
    out[e] = o;
    if (BF16OUT) {
        bf16x4 ob = { (__bf16)o.x, (__bf16)o.y, (__bf16)o.z, (__bf16)o.w };
        outb[e] = ob;
    }
}

// ---------------- launch ----------------
extern "C" void kernel_launch(void* const* d_in, const int* in_sizes, int n_in,
                              void* d_out, int out_size, void* d_ws, size_t ws_size,
                              hipStream_t stream)
{
    const float* src     = (const float*)d_in[0];
    const float* pos     = (const float*)d_in[1];
    const float* refp    = (const float*)d_in[2];
    const float* W_value = (const float*)d_in[5];
    const float* b_value = (const float*)d_in[6];
    const float* W_off   = (const float*)d_in[7];
    const float* b_off   = (const float*)d_in[8];
    const float* W_attn  = (const float*)d_in[9];
    const float* b_attn  = (const float*)d_in[10];
    const float* W_out   = (const float*)d_in[11];
    const float* b_out   = (const float*)d_in[12];
    const float* W1      = (const float*)d_in[13];
    const float* b1      = (const float*)d_in[14];
    const float* W2      = (const float*)d_in[15];
    const float* b2      = (const float*)d_in[16];
    const float* g1      = (const float*)d_in[17];
    const float* be1     = (const float*)d_in[18];
    const float* g2      = (const float*)d_in[19];
    const float* be2     = (const float*)d_in[20];
    float* outp = (float*)d_out;

    const int M = M_TOK;
    char* ws = (char*)d_ws;
    const size_t R2 = (size_t)M_PAD * 512;   // bytes of one [Mpad,256] bf16 buffer

    __bf16* src_b = (__bf16*)(ws);                    // R2
    __bf16* q_b   = (__bf16*)(ws + R2);               // R2
    __bf16* val_b = (__bf16*)(ws + 2 * R2);           // R2
    __bf16* oa    = (__bf16*)(ws + 3 * R2);           // 1.5*R2  [Mpad,384]
    __bf16* samp  = (__bf16*)(ws + 9 * R2 / 2);       // R2
    float*  src2  = (float*)(ws + 11 * R2 / 2);       // 2*R2 fp32
    float*  f2    = (float*)(ws + 11 * R2 / 2);       // overlay src2 (dead after LN1)
    float*  x     = (float*)(ws + 15 * R2 / 2);       // 2*R2 fp32
    __bf16* x_b   = (__bf16*)(ws + 19 * R2 / 2);      // R2
    __bf16* hbuf  = (__bf16*)(ws);                    // 4*R2 overlay (front-end dead by FFN1)
    __bf16* wbase = (__bf16*)(ws + 21 * R2 / 2);
    __bf16* Wt_value = wbase;                          // [256][256]
    __bf16* Wt_oa    = wbase + 65536;                  // [384][256]
    __bf16* Wt_out   = wbase + 163840;                 // [256][256]
    __bf16* Wt1      = wbase + 229376;                 // [1024][256]
    __bf16* Wt2      = wbase + 491520;                 // [256][1024]
    float*  bias_oa  = (float*)(wbase + 753664);       // [384]

    const dim3 blk(256);
    const int n4 = M * 256 / 4;

    cvt_src_q<<<dim3((n4 + 255) / 256), blk, 0, stream>>>(
        (const float4*)src, (const float4*)pos, (bf16x4*)src_b, (bf16x4*)q_b, n4);
    transpose_all<<<dim3(737), dim3(32, 8), 0, stream>>>(
        W_value, W_off, W_attn, W_out, W1, W2,
        Wt_value, Wt_oa, Wt_oa + 65536, Wt_out, Wt1, Wt2,
        b_off, b_attn, bias_oa);

    const int gm = M_PAD / 128;  // 208

    gemm_mfma<__bf16, false, 2><<<dim3(2, gm), blk, 0, stream>>>(src_b, Wt_value, b_value, val_b, M, 256, 256);
    gemm_mfma<__bf16, false, 2><<<dim3(3, gm), blk, 0, stream>>>(q_b,   Wt_oa,    bias_oa, oa,    M, 384, 256);

    msda_sample<<<dim3(M / 2), blk, 0, stream>>>(val_b, oa, refp, samp);

    gemm_mfma<float,  false, 2><<<dim3(2, gm), blk, 0, stream>>>(samp, Wt_out, b_out, src2, M, 256, 256);
    add_ln<true><<<dim3(M / 4), blk, 0, stream>>>(
        (const float4*)src, (const float4*)src2, (const float4*)g1, (const float4*)be1,
        (float4*)x, (bf16x4*)x_b);
    gemm_mfma<__bf16, true,  2><<<dim3(8, gm), blk, 0, stream>>>(x_b,  Wt1, b1, hbuf, M, 1024, 256);
    gemm_mfma<float,  false, 2><<<dim3(2, gm), blk, 0, stream>>>(hbuf, Wt2, b2, f2,   M, 256, 1024);
    add_ln<false><<<dim3(M / 4), blk, 0, stream>>>(
        (const float4*)x, (const float4*)f2, (const float4*)g2, (const float4*)be2,
        (float4*)outp, nullptr);
}

// Round 4
// 349.498 us; speedup vs baseline: 2.7111x; 1.1587x over previous
//
#include <hip/hip_runtime.h>
#include <hip/hip_bf16.h>
#include <cstdint>

// ---------------- static problem config ----------------
#define D_MODEL   256
#define N_HEADS   8
#define N_LEVELS  4
#define N_POINTS  4
#define D_FFN     1024
#define D_HEAD    32
#define LEN_IN    13294          // 100*100 + 50*50 + 25*25 + 13*13
#define NBATCH    2
#define M_TOK     (NBATCH * LEN_IN)   // 26588
#define M_PAD     26624               // 208 * 128

__constant__ int c_lvl_h[4] = {100, 50, 25, 13};
__constant__ int c_lvl_w[4] = {100, 50, 25, 13};
__constant__ int c_lvl_s[4] = {0, 10000, 12500, 13125};

typedef __attribute__((ext_vector_type(8))) __bf16 bf16x8;
typedef __attribute__((ext_vector_type(4))) __bf16 bf16x4;
typedef __attribute__((ext_vector_type(2))) __bf16 bf16x2;
typedef __attribute__((ext_vector_type(4))) float  f32x4;
typedef __attribute__((ext_vector_type(4))) uint32_t u32x4;

__device__ __forceinline__ float bflo(uint32_t w) { return __uint_as_float(w << 16); }
__device__ __forceinline__ float bfhi(uint32_t w) { return __uint_as_float(w & 0xffff0000u); }

// async global->LDS, 16B per lane; lds base wave-uniform (lane i lands at base + i*16)
__device__ __forceinline__ void lds_direct16(const void* g, void* l) {
    __builtin_amdgcn_global_load_lds(
        (const __attribute__((address_space(1))) uint32_t*)(uintptr_t)g,
        (__attribute__((address_space(3))) uint32_t*)(uintptr_t)l,
        16, 0, 0);
}

// ---------------- fp32 -> bf16 conversions ----------------
__global__ __launch_bounds__(256) void cvt_src_q(
    const float4* __restrict__ src, const float4* __restrict__ pos,
    bf16x4* __restrict__ sb, bf16x4* __restrict__ qb, int n4)
{
    const int i = blockIdx.x * 256 + threadIdx.x;
    if (i >= n4) return;
    const float4 s = src[i];
    const float4 p = pos[i];
    bf16x4 sv = { (__bf16)s.x, (__bf16)s.y, (__bf16)s.z, (__bf16)s.w };
    bf16x4 qv = { (__bf16)(s.x + p.x), (__bf16)(s.y + p.y),
                  (__bf16)(s.z + p.z), (__bf16)(s.w + p.w) };
    sb[i] = sv;
    qb[i] = qv;
}

// ---------------- all weight transposes + bias concat in ONE dispatch ----------------
__global__ __launch_bounds__(256) void transpose_all(
    const float* __restrict__ s0, const float* __restrict__ s1, const float* __restrict__ s2,
    const float* __restrict__ s3, const float* __restrict__ s4, const float* __restrict__ s5,
    __bf16* __restrict__ d0, __bf16* __restrict__ d1, __bf16* __restrict__ d2,
    __bf16* __restrict__ d3, __bf16* __restrict__ d4, __bf16* __restrict__ d5,
    const float* __restrict__ b_off, const float* __restrict__ b_attn,
    float* __restrict__ bias_oa)
{
    const int tx = threadIdx.x;
    const int ty = threadIdx.y;
    const int tid = ty * 32 + tx;
    const int b = blockIdx.x;
    if (b == 736) {   // bias concat: [b_off(256) | b_attn(128)]
        if (tid < 256) bias_oa[tid] = b_off[tid];
        if (tid < 128) bias_oa[256 + tid] = b_attn[tid];
        return;
    }
    const int starts[7] = {0, 64, 128, 160, 224, 480, 736};
    const int Ks[6] = {256, 256, 256, 256, 256, 1024};
    const int Ns[6] = {256, 256, 128, 256, 1024, 256};
    const float* srcs[6] = {s0, s1, s2, s3, s4, s5};
    __bf16* dsts[6] = {d0, d1, d2, d3, d4, d5};
    int i = 0;
    while (b >= starts[i + 1]) ++i;
    const int t = b - starts[i];
    const int K = Ks[i], N = Ns[i];
    const float* W = srcs[i];
    __bf16* Wt = dsts[i];
    const int ntx = N >> 5;
    const int n0 = (t % ntx) * 32;
    const int k0 = (t / ntx) * 32;

    __shared__ float tl[32][33];
    #pragma unroll
    for (int j = 0; j < 4; ++j)
        tl[ty + j * 8][tx] = W[(size_t)(k0 + ty + j * 8) * N + n0 + tx];
    __syncthreads();
    #pragma unroll
    for (int j = 0; j < 4; ++j)
        Wt[(size_t)(n0 + ty + j * 8) * K + k0 + tx] = (__bf16)tl[tx][ty + j * 8];
}

// ---------------- bf16 MFMA GEMM (m97 structure, compile-time K) ----------------
// C[M,N] = act(A @ Bt^T + bias); A [Mpad,K] bf16 row-major, Bt [N,K] bf16 row-major.
// 128x128 tile, 256 thr = 4 waves (2x2), each wave 4x4 of 16x16x32 MFMA. NP k-panels/barrier.
template <typename OutT, bool RELU, int NP, int K>
__global__ __launch_bounds__(256) void gemm_mfma(
    const __bf16* __restrict__ A, const __bf16* __restrict__ Bt,
    const float* __restrict__ bias, OutT* __restrict__ C,
    int M, int N)
{
    __shared__ __bf16 As[NP * 128 * 32];
    __shared__ __bf16 Bs[NP * 128 * 32];

    const int tid  = threadIdx.x;
    const int lane = tid & 63;
    const int wv   = tid >> 6;
    const int bm   = blockIdx.y * 128;
    const int bn   = blockIdx.x * 128;
    const int wm   = (wv >> 1) * 64;
    const int wn   = (wv & 1) * 64;
    const int srow = lane >> 2;        // staging row within 16-row chunk
    const int skc  = (lane & 3) * 8;   // staging k-chunk (elems)
    const int fm   = lane & 15;        // fragment row/col
    const int fko  = (lane >> 4) * 8;  // fragment k offset

    f32x4 acc[4][4] = {};

    #pragma unroll
    for (int k0 = 0; k0 < K; k0 += 32 * NP) {
        #pragma unroll
        for (int p = 0; p < NP; ++p) {
            #pragma unroll
            for (int c = 0; c < 2; ++c) {
                const int r = wv * 32 + c * 16;
                lds_direct16(A  + (size_t)(bm + r + srow) * K + k0 + p * 32 + skc, As + p * 4096 + r * 32);
                lds_direct16(Bt + (size_t)(bn + r + srow) * K + k0 + p * 32 + skc, Bs + p * 4096 + r * 32);
            }
        }
        __syncthreads();

        #pragma unroll
        for (int p = 0; p < NP; ++p) {
            bf16x8 af[4], bfr[4];
            #pragma unroll
            for (int t = 0; t < 4; ++t) {
                af[t]  = *(const bf16x8*)(As + p * 4096 + (wm + t * 16 + fm) * 32 + fko);
                bfr[t] = *(const bf16x8*)(Bs + p * 4096 + (wn + t * 16 + fm) * 32 + fko);
            }
            #pragma unroll
            for (int mt = 0; mt < 4; ++mt)
                #pragma unroll
                for (int nt = 0; nt < 4; ++nt)
                    acc[mt][nt] = __builtin_amdgcn_mfma_f32_16x16x32_bf16(
                        af[mt], bfr[nt], acc[mt][nt], 0, 0, 0);
        }
        __syncthreads();
    }

    // C/D layout: col = lane&15, row = (lane>>4)*4 + reg  [m89-verified]
    const int ecol = lane & 15;
    const int erow = (lane >> 4) * 4;
    #pragma unroll
    for (int nt = 0; nt < 4; ++nt) {
        const int col = bn + wn + nt * 16 + ecol;
        const float bv = bias[col];
        #pragma unroll
        for (int mt = 0; mt < 4; ++mt) {
            #pragma unroll
            for (int r = 0; r < 4; ++r) {
                const int row = bm + wm + mt * 16 + erow + r;
                if (row < M) {
                    float v = acc[mt][nt][r] + bv;
                    if (RELU) v = fmaxf(v, 0.f);
                    C[(size_t)row * N + col] = (OutT)v;
                }
            }
        }
    }
}

// ---------------- deformable sampling ----------------
// One token per block (round-2 proven structure), 256 thr = 8 heads x 32 channels.
// Setup computes (idx, softmax*bilinear wt) packed 8B in LDS; gather reads 2 corners
// per ds_read_b128, then scalar ushort gather + shift + fma per corner-channel.
struct alignas(8) IW { uint32_t idx; float wt; };

__global__ __launch_bounds__(256) void msda_sample(
    const __bf16* __restrict__ value, // [Mpad, 256] bf16
    const __bf16* __restrict__ oa,    // [Mpad, 384] bf16: [off(256) | attn(128)]
    const float* __restrict__ refp,   // [M, 4, 2]
    __bf16* __restrict__ out)         // [Mpad, 256] bf16
{
    __shared__ IW    sc[8][16][4];    // 4 KB
    __shared__ float sw[8][16];       // softmax weights

    const int row = blockIdx.x;
    const int tid = threadIdx.x;

    uint32_t cidx[4];
    float    cwt[4];
    const int h  = tid >> 4;          // setup: head  (tid<128)
    const int lp = tid & 15;          // setup: level*4+point

    // phase 1a (threads 0-127, registers only): corner idx + bilinear weights
    if (tid < 128) {
        const int l  = lp >> 2;
        const int Ww = c_lvl_w[l];
        const int Hh = c_lvl_h[l];
        const uint32_t opk = *(const uint32_t*)(oa + (size_t)row * 384 + h * 32 + lp * 2);
        const float ox = bflo(opk), oy = bfhi(opk);
        const float rx = refp[((size_t)row * 4 + l) * 2 + 0];
        const float ry = refp[((size_t)row * 4 + l) * 2 + 1];
        const float x = (rx + ox / (float)Ww) * (float)Ww - 0.5f;
        const float y = (ry + oy / (float)Hh) * (float)Hh - 0.5f;
        const float xf = floorf(x), yf = floorf(y);
        const float fx = x - xf,    fy = y - yf;
        const int x0 = (int)xf, y0 = (int)yf;
        const int n  = row / LEN_IN;
        const int base = n * LEN_IN + c_lvl_s[l];
        #pragma unroll
        for (int c = 0; c < 4; ++c) {
            const int dx = c & 1, dy = c >> 1;
            const int xi = x0 + dx, yi = y0 + dy;
            const bool valid = (xi >= 0) & (xi < Ww) & (yi >= 0) & (yi < Hh);
            cidx[c] = valid ? (uint32_t)(base + yi * Ww + xi) * 256u : 0u;
            cwt[c]  = valid ? (dx ? fx : 1.f - fx) * (dy ? fy : 1.f - fy) : 0.f;
        }
    } else if (tid < 136) {
        // phase 1b (8 threads, concurrent): per-head softmax of 16 logits
        const int h2 = tid - 128;
        const __bf16* ap = oa + (size_t)row * 384 + 256 + h2 * 16;
        float e[16], mx = -1e30f;
        #pragma unroll
        for (int i = 0; i < 16; ++i) { e[i] = (float)ap[i]; mx = fmaxf(mx, e[i]); }
        float s = 0.f;
        #pragma unroll
        for (int i = 0; i < 16; ++i) { e[i] = __expf(e[i] - mx); s += e[i]; }
        const float inv = 1.f / s;
        #pragma unroll
        for (int i = 0; i < 16; ++i) sw[h2][i] = e[i] * inv;
    }
    __syncthreads();
    // phase 2: fold softmax, single packed write (2 x b128 per thread)
    if (tid < 128) {
        const float a = sw[h][lp];
        IW w0 = { cidx[0], cwt[0] * a };
        IW w1 = { cidx[1], cwt[1] * a };
        IW w2 = { cidx[2], cwt[2] * a };
        IW w3 = { cidx[3], cwt[3] * a };
        u32x4 pk0 = { w0.idx, __float_as_uint(w0.wt), w1.idx, __float_as_uint(w1.wt) };
        u32x4 pk1 = { w2.idx, __float_as_uint(w2.wt), w3.idx, __float_as_uint(w3.wt) };
        *(u32x4*)&sc[h][lp][0] = pk0;
        *(u32x4*)&sc[h][lp][2] = pk1;
    }
    __syncthreads();

    // phase 3: gather. thread = channel; 2 h per wave -> LDS reads broadcast (2-way, free)
    const uint16_t* __restrict__ vu = (const uint16_t*)value;
    const int gh  = tid >> 5;
    const uint32_t col = (uint32_t)tid;
    float acc = 0.f;
    #pragma unroll
    for (int q = 0; q < 16; ++q) {
        const u32x4 a = *(const u32x4*)&sc[gh][q][0];
        const u32x4 b = *(const u32x4*)&sc[gh][q][2];
        acc += __uint_as_float(a.y) * __uint_as_float((uint32_t)vu[a.x + col] << 16);
        acc += __uint_as_float(a.w) * __uint_as_float((uint32_t)vu[a.z + col] << 16);
        acc += __uint_as_float(b.y) * __uint_as_float((uint32_t)vu[b.x + col] << 16);
        acc += __uint_as_float(b.w) * __uint_as_float((uint32_t)vu[b.z + col] << 16);
    }
    out[(size_t)row * 256 + tid] = (__bf16)acc;
}

// ---------------- residual + LayerNorm (wave per row, float4) ----------------
// a: fp32 residual; b: bf16 or fp32 branch; out fp32 (+ optional bf16 copy)
template <bool BF16OUT, bool BBF16>
__global__ __launch_bounds__(256) void add_ln(
    const float4* __restrict__ a, const void* __restrict__ braw,
    const float4* __restrict__ g4, const float4* __restrict__ be4,
    float4* __restrict__ out, bf16x4* __restrict__ outb)
{
    const int tid  = threadIdx.x;
    const int row  = blockIdx.x * 4 + (tid >> 6);
    const int lane = tid & 63;
    const size_t e = (size_t)row * 64 + lane;
    const float4 va = a[e];
    float4 vb;
    if (BBF16) {
        const bf16x4 t = ((const bf16x4*)braw)[e];
        vb = { (float)t[0], (float)t[1], (float)t[2], (float)t[3] };
    } else {
        vb = ((const float4*)braw)[e];
    }
    float4 v = { va.x + vb.x, va.y + vb.y, va.z + vb.z, va.w + vb.w };

    float s  = v.x + v.y + v.z + v.w;
    float s2 = v.x * v.x + v.y * v.y + v.z * v.z + v.w * v.w;
    #pragma unroll
    for (int o = 32; o > 0; o >>= 1) {
        s  += __shfl_down(s, o);
        s2 += __shfl_down(s2, o);
    }
    s  = __shfl(s, 0);
    s2 = __shfl(s2, 0);
    const float mu  = s * (1.f / 256.f);
    const float var = s2 * (1.f / 256.f) - mu * mu;
    const float rs  = rsqrtf(var + 1e-5f);
    const float4 g = g4[lane];
    const float4 be = be4[lane];
    float4 o;
    o.x = (v.x - mu) * rs * g.x + be.x;
    o.y = (v.y - mu) * rs * g.y + be.y;
    o.z = (v.z - mu) * rs * g.z + be.z;
    o.w = (v.w - mu) * rs * g.w + be.w;
    out[e] = o;
    if (BF16OUT) {
        bf16x4 ob = { (__bf16)o.x, (__bf16)o.y, (__bf16)o.z, (__bf16)o.w };
        outb[e] = ob;
    }
}

// ---------------- launch ----------------
extern "C" void kernel_launch(void* const* d_in, const int* in_sizes, int n_in,
                              void* d_out, int out_size, void* d_ws, size_t ws_size,
                              hipStream_t stream)
{
    const float* src     = (const float*)d_in[0];
    const float* pos     = (const float*)d_in[1];
    const float* refp    = (const float*)d_in[2];
    const float* W_value = (const float*)d_in[5];
    const float* b_value = (const float*)d_in[6];
    const float* W_off   = (const float*)d_in[7];
    const float* b_off   = (const float*)d_in[8];
    const float* W_attn  = (const float*)d_in[9];
    const float* b_attn  = (const float*)d_in[10];
    const float* W_out   = (const float*)d_in[11];
    const float* b_out   = (const float*)d_in[12];
    const float* W1      = (const float*)d_in[13];
    const float* b1      = (const float*)d_in[14];
    const float* W2      = (const float*)d_in[15];
    const float* b2      = (const float*)d_in[16];
    const float* g1      = (const float*)d_in[17];
    const float* be1     = (const float*)d_in[18];
    const float* g2      = (const float*)d_in[19];
    const float* be2     = (const float*)d_in[20];
    float* outp = (float*)d_out;

    const int M = M_TOK;
    char* ws = (char*)d_ws;
    const size_t R2 = (size_t)M_PAD * 512;   // bytes of one [Mpad,256] bf16 buffer

    __bf16* src_b = (__bf16*)(ws);                    // R2
    __bf16* q_b   = (__bf16*)(ws + R2);               // R2
    __bf16* val_b = (__bf16*)(ws + 2 * R2);           // R2
    __bf16* oa    = (__bf16*)(ws + 3 * R2);           // 1.5*R2  [Mpad,384]
    __bf16* samp  = (__bf16*)(ws + 9 * R2 / 2);       // R2
    __bf16* src2b = (__bf16*)(ws + 11 * R2 / 2);      // R2 (bf16)
    __bf16* f2b   = (__bf16*)(ws + 11 * R2 / 2);      // overlay src2b (dead after LN1)
    float*  x     = (float*)(ws + 13 * R2 / 2);       // 2*R2 fp32
    __bf16* x_b   = (__bf16*)(ws + 17 * R2 / 2);      // R2
    __bf16* hbuf  = (__bf16*)(ws);                    // 4*R2 overlay (front-end dead by FFN1)
    __bf16* wbase = (__bf16*)(ws + 19 * R2 / 2);
    __bf16* Wt_value = wbase;                          // [256][256]
    __bf16* Wt_oa    = wbase + 65536;                  // [384][256]
    __bf16* Wt_out   = wbase + 163840;                 // [256][256]
    __bf16* Wt1      = wbase + 229376;                 // [1024][256]
    __bf16* Wt2      = wbase + 491520;                 // [256][1024]
    float*  bias_oa  = (float*)(wbase + 753664);       // [384]

    const dim3 blk(256);
    const int n4 = M * 256 / 4;

    cvt_src_q<<<dim3((n4 + 255) / 256), blk, 0, stream>>>(
        (const float4*)src, (const float4*)pos, (bf16x4*)src_b, (bf16x4*)q_b, n4);
    transpose_all<<<dim3(737), dim3(32, 8), 0, stream>>>(
        W_value, W_off, W_attn, W_out, W1, W2,
        Wt_value, Wt_oa, Wt_oa + 65536, Wt_out, Wt1, Wt2,
        b_off, b_attn, bias_oa);

    const int gm = M_PAD / 128;  // 208

    gemm_mfma<__bf16, false, 2, 256><<<dim3(2, gm), blk, 0, stream>>>(src_b, Wt_value, b_value, val_b, M, 256);
    gemm_mfma<__bf16, false, 2, 256><<<dim3(3, gm), blk, 0, stream>>>(q_b,   Wt_oa,    bias_oa, oa,    M, 384);

    msda_sample<<<dim3(M), blk, 0, stream>>>(val_b, oa, refp, samp);

    gemm_mfma<__bf16, false, 2, 256><<<dim3(2, gm), blk, 0, stream>>>(samp, Wt_out, b_out, src2b, M, 256);
    add_ln<true, true><<<dim3(M / 4), blk, 0, stream>>>(
        (const float4*)src, (const void*)src2b, (const float4*)g1, (const float4*)be1,
        (float4*)x, (bf16x4*)x_b);
    gemm_mfma<__bf16, true,  2, 256><<<dim3(8, gm), blk, 0, stream>>>(x_b,  Wt1, b1, hbuf, M, 1024);
    gemm_mfma<__bf16, false, 2, 1024><<<dim3(2, gm), blk, 0, stream>>>(hbuf, Wt2, b2, f2b, M, 256);
    add_ln<false, true><<<dim3(M / 4), blk, 0, stream>>>(
        (const float4*)x, (const void*)f2b, (const float4*)g2, (const float4*)be2,
        (float4*)outp, nullptr);
}

// Round 5
// 348.235 us; speedup vs baseline: 2.7209x; 1.0036x over previous
//
#include <hip/hip_runtime.h>
#include <hip/hip_bf16.h>
#include <cstdint>

// ---------------- static problem config ----------------
#define D_MODEL   256
#define N_HEADS   8
#define N_LEVELS  4
#define N_POINTS  4
#define D_FFN     1024
#define D_HEAD    32
#define LEN_IN    13294          // 100*100 + 50*50 + 25*25 + 13*13
#define NBATCH    2
#define M_TOK     (NBATCH * LEN_IN)   // 26588
#define M_PAD     26624               // 208 * 128

__constant__ int c_lvl_h[4] = {100, 50, 25, 13};
__constant__ int c_lvl_w[4] = {100, 50, 25, 13};
__constant__ int c_lvl_s[4] = {0, 10000, 12500, 13125};

typedef __attribute__((ext_vector_type(8))) __bf16 bf16x8;
typedef __attribute__((ext_vector_type(4))) __bf16 bf16x4;
typedef __attribute__((ext_vector_type(4))) float  f32x4;
typedef __attribute__((ext_vector_type(4))) uint32_t u32x4;

__device__ __forceinline__ float bflo(uint32_t w) { return __uint_as_float(w << 16); }
__device__ __forceinline__ float bfhi(uint32_t w) { return __uint_as_float(w & 0xffff0000u); }

// async global->LDS, 16B per lane; lds base wave-uniform (lane i lands at base + i*16)
__device__ __forceinline__ void lds_direct16(const void* g, void* l) {
    __builtin_amdgcn_global_load_lds(
        (const __attribute__((address_space(1))) uint32_t*)(uintptr_t)g,
        (__attribute__((address_space(3))) uint32_t*)(uintptr_t)l,
        16, 0, 0);
}

// ---------------- prep: weight transposes + bias concat + src/q cvt, ONE dispatch ----------------
// blocks 0..735: weight transpose tiles; 736: bias concat; 737+: cvt_src_q
__global__ __launch_bounds__(256) void prep(
    const float* __restrict__ s0, const float* __restrict__ s1, const float* __restrict__ s2,
    const float* __restrict__ s3, const float* __restrict__ s4, const float* __restrict__ s5,
    __bf16* __restrict__ d0, __bf16* __restrict__ d1, __bf16* __restrict__ d2,
    __bf16* __restrict__ d3, __bf16* __restrict__ d4, __bf16* __restrict__ d5,
    const float* __restrict__ b_off, const float* __restrict__ b_attn,
    float* __restrict__ bias_oa,
    const float4* __restrict__ src, const float4* __restrict__ pos,
    bf16x4* __restrict__ sb, bf16x4* __restrict__ qb, int n4)
{
    const int tid = threadIdx.x;
    const int b = blockIdx.x;
    if (b >= 737) {   // cvt path
        const int i = (b - 737) * 256 + tid;
        if (i >= n4) return;
        const float4 s = src[i];
        const float4 p = pos[i];
        bf16x4 sv = { (__bf16)s.x, (__bf16)s.y, (__bf16)s.z, (__bf16)s.w };
        bf16x4 qv = { (__bf16)(s.x + p.x), (__bf16)(s.y + p.y),
                      (__bf16)(s.z + p.z), (__bf16)(s.w + p.w) };
        sb[i] = sv;
        qb[i] = qv;
        return;
    }
    if (b == 736) {   // bias concat: [b_off(256) | b_attn(128)]
        if (tid < 256) bias_oa[tid] = b_off[tid];
        if (tid < 128) bias_oa[256 + tid] = b_attn[tid];
        return;
    }
    const int tx = tid & 31;
    const int ty = tid >> 5;
    const int starts[7] = {0, 64, 128, 160, 224, 480, 736};
    const int Ks[6] = {256, 256, 256, 256, 256, 1024};
    const int Ns[6] = {256, 256, 128, 256, 1024, 256};
    const float* srcs[6] = {s0, s1, s2, s3, s4, s5};
    __bf16* dsts[6] = {d0, d1, d2, d3, d4, d5};
    int i = 0;
    while (b >= starts[i + 1]) ++i;
    const int t = b - starts[i];
    const int K = Ks[i], N = Ns[i];
    const float* W = srcs[i];
    __bf16* Wt = dsts[i];
    const int ntx = N >> 5;
    const int n0 = (t % ntx) * 32;
    const int k0 = (t / ntx) * 32;

    __shared__ float tl[32][33];
    #pragma unroll
    for (int j = 0; j < 4; ++j)
        tl[ty + j * 8][tx] = W[(size_t)(k0 + ty + j * 8) * N + n0 + tx];
    __syncthreads();
    #pragma unroll
    for (int j = 0; j < 4; ++j)
        Wt[(size_t)(n0 + ty + j * 8) * K + k0 + tx] = (__bf16)tl[tx][ty + j * 8];
}

// ---------------- bf16 MFMA GEMM core (m97 structure, 128x128 tile) ----------------
template <typename OutT, bool RELU, int NP, int K>
__device__ __forceinline__ void gemm_core(
    const __bf16* __restrict__ A, const __bf16* __restrict__ Bt,
    const float* __restrict__ bias, OutT* __restrict__ C,
    int M, int N, int bm, int bn)
{
    __shared__ __bf16 As[NP * 128 * 32];
    __shared__ __bf16 Bs[NP * 128 * 32];

    const int tid  = threadIdx.x;
    const int lane = tid & 63;
    const int wv   = tid >> 6;
    const int wm   = (wv >> 1) * 64;
    const int wn   = (wv & 1) * 64;
    const int srow = lane >> 2;
    const int skc  = (lane & 3) * 8;
    const int fm   = lane & 15;
    const int fko  = (lane >> 4) * 8;

    f32x4 acc[4][4] = {};

    for (int k0 = 0; k0 < K; k0 += 32 * NP) {
        #pragma unroll
        for (int p = 0; p < NP; ++p) {
            #pragma unroll
            for (int c = 0; c < 2; ++c) {
                const int r = wv * 32 + c * 16;
                lds_direct16(A  + (size_t)(bm + r + srow) * K + k0 + p * 32 + skc, As + p * 4096 + r * 32);
                lds_direct16(Bt + (size_t)(bn + r + srow) * K + k0 + p * 32 + skc, Bs + p * 4096 + r * 32);
            }
        }
        __syncthreads();

        #pragma unroll
        for (int p = 0; p < NP; ++p) {
            bf16x8 af[4], bfr[4];
            #pragma unroll
            for (int t = 0; t < 4; ++t) {
                af[t]  = *(const bf16x8*)(As + p * 4096 + (wm + t * 16 + fm) * 32 + fko);
                bfr[t] = *(const bf16x8*)(Bs + p * 4096 + (wn + t * 16 + fm) * 32 + fko);
            }
            #pragma unroll
            for (int mt = 0; mt < 4; ++mt)
                #pragma unroll
                for (int nt = 0; nt < 4; ++nt)
                    acc[mt][nt] = __builtin_amdgcn_mfma_f32_16x16x32_bf16(
                        af[mt], bfr[nt], acc[mt][nt], 0, 0, 0);
        }
        __syncthreads();
    }

    // C/D layout: col = lane&15, row = (lane>>4)*4 + reg  [m89-verified]
    const int ecol = lane & 15;
    const int erow = (lane >> 4) * 4;
    #pragma unroll
    for (int nt = 0; nt < 4; ++nt) {
        const int col = bn + wn + nt * 16 + ecol;
        const float bv = bias[col];
        #pragma unroll
        for (int mt = 0; mt < 4; ++mt) {
            #pragma unroll
            for (int r = 0; r < 4; ++r) {
                const int row = bm + wm + mt * 16 + erow + r;
                if (row < M) {
                    float v = acc[mt][nt][r] + bv;
                    if (RELU) v = fmaxf(v, 0.f);
                    C[(size_t)row * N + col] = (OutT)v;
                }
            }
        }
    }
}

// plain GEMM kernel (FFN1)
template <typename OutT, bool RELU, int NP, int K>
__global__ __launch_bounds__(256) void gemm_mfma(
    const __bf16* __restrict__ A, const __bf16* __restrict__ Bt,
    const float* __restrict__ bias, OutT* __restrict__ C, int M, int N)
{
    gemm_core<OutT, RELU, NP, K>(A, Bt, bias, C, M, N, blockIdx.y * 128, blockIdx.x * 128);
}

// front GEMM: blocks x<2 -> value (src_b @ Wt_value), x>=2 -> oa (q_b @ Wt_oa)
__global__ __launch_bounds__(256) void gemm_front(
    const __bf16* __restrict__ A0, const __bf16* __restrict__ B0,
    const float* __restrict__ bi0, __bf16* __restrict__ C0,
    const __bf16* __restrict__ A1, const __bf16* __restrict__ B1,
    const float* __restrict__ bi1, __bf16* __restrict__ C1, int M)
{
    const int bx = blockIdx.x;
    if (bx < 2)
        gemm_core<__bf16, false, 2, 256>(A0, B0, bi0, C0, M, 256, blockIdx.y * 128, bx * 128);
    else
        gemm_core<__bf16, false, 2, 256>(A1, B1, bi1, C1, M, 384, blockIdx.y * 128, (bx - 2) * 128);
}

// ---------------- GEMM + residual + LayerNorm fused (64x256 tile, 4 waves) ----------------
// C_ln = LN((A @ Bt^T + bias) + res) * gamma + beta ; full 256-col rows per block.
template <typename OutT, int K>
__global__ __launch_bounds__(256) void gemm_ln(
    const __bf16* __restrict__ A, const __bf16* __restrict__ Bt,
    const float* __restrict__ bias, const __bf16* __restrict__ res,
    const float* __restrict__ gamma, const float* __restrict__ beta,
    OutT* __restrict__ Cout, int M)
{
    constexpr int NP = 2;
    __shared__ __bf16 As[NP * 64 * 32];    //  8 KB
    __shared__ __bf16 Bs[NP * 256 * 32];   // 32 KB
    __shared__ float lnsum[64][4];
    __shared__ float lnsq[64][4];
    __shared__ float lnstat[64][2];

    const int tid  = threadIdx.x;
    const int lane = tid & 63;
    const int wv   = tid >> 6;         // 0..3
    const int bm   = blockIdx.x * 64;
    const int wn   = wv * 64;          // wave owns cols [wn, wn+64)
    const int srow = lane >> 2;
    const int skc  = (lane & 3) * 8;
    const int fm   = lane & 15;
    const int fko  = (lane >> 4) * 8;

    f32x4 acc[4][4] = {};

    for (int k0 = 0; k0 < K; k0 += 32 * NP) {
        #pragma unroll
        for (int p = 0; p < NP; ++p) {
            if (wv == 0) { /* nothing extra */ }
            // A: 64 rows, 4 waves x 16 rows
            lds_direct16(A + (size_t)(bm + wv * 16 + srow) * K + k0 + p * 32 + skc,
                         As + p * 2048 + (wv * 16) * 32);
            // B: 256 rows, 4 waves x 64 rows (4 chunks of 16)
            #pragma unroll
            for (int c = 0; c < 4; ++c) {
                const int r = wv * 64 + c * 16;
                lds_direct16(Bt + (size_t)(r + srow) * K + k0 + p * 32 + skc,
                             Bs + p * 8192 + r * 32);
            }
        }
        __syncthreads();

        #pragma unroll
        for (int p = 0; p < NP; ++p) {
            bf16x8 af[4], bfr[4];
            #pragma unroll
            for (int t = 0; t < 4; ++t) {
                af[t]  = *(const bf16x8*)(As + p * 2048 + (t * 16 + fm) * 32 + fko);
                bfr[t] = *(const bf16x8*)(Bs + p * 8192 + (wn + t * 16 + fm) * 32 + fko);
            }
            #pragma unroll
            for (int mt = 0; mt < 4; ++mt)
                #pragma unroll
                for (int nt = 0; nt < 4; ++nt)
                    acc[mt][nt] = __builtin_amdgcn_mfma_f32_16x16x32_bf16(
                        af[mt], bfr[nt], acc[mt][nt], 0, 0, 0);
        }
        __syncthreads();
    }

    const int ecol = lane & 15;
    const int erow = (lane >> 4) * 4;

    // bias + residual (in place)
    float g4[4], b4[4];
    #pragma unroll
    for (int nt = 0; nt < 4; ++nt) {
        const int col = wn + nt * 16 + ecol;
        g4[nt] = gamma[col];
        b4[nt] = beta[col];
        const float bv = bias[col];
        #pragma unroll
        for (int mt = 0; mt < 4; ++mt) {
            #pragma unroll
            for (int r = 0; r < 4; ++r) {
                const int row = bm + mt * 16 + erow + r;
                acc[mt][nt][r] += bv + (float)res[(size_t)row * 256 + col];
            }
        }
    }

    // per-row sums: lane partial over nt, then shfl over the 16-lane quarter
    #pragma unroll
    for (int mt = 0; mt < 4; ++mt) {
        #pragma unroll
        for (int r = 0; r < 4; ++r) {
            float s  = acc[mt][0][r] + acc[mt][1][r] + acc[mt][2][r] + acc[mt][3][r];
            float s2 = acc[mt][0][r] * acc[mt][0][r] + acc[mt][1][r] * acc[mt][1][r]
                     + acc[mt][2][r] * acc[mt][2][r] + acc[mt][3][r] * acc[mt][3][r];
            #pragma unroll
            for (int o = 1; o < 16; o <<= 1) {
                s  += __shfl_xor(s, o);
                s2 += __shfl_xor(s2, o);
            }
            if (ecol == 0) {
                const int rl = mt * 16 + erow + r;
                lnsum[rl][wv] = s;
                lnsq[rl][wv]  = s2;
            }
        }
    }
    __syncthreads();
    if (tid < 64) {
        const float s  = lnsum[tid][0] + lnsum[tid][1] + lnsum[tid][2] + lnsum[tid][3];
        const float s2 = lnsq[tid][0] + lnsq[tid][1] + lnsq[tid][2] + lnsq[tid][3];
        const float mu = s * (1.f / 256.f);
        const float var = s2 * (1.f / 256.f) - mu * mu;
        lnstat[tid][0] = mu;
        lnstat[tid][1] = rsqrtf(var + 1e-5f);
    }
    __syncthreads();

    #pragma unroll
    for (int mt = 0; mt < 4; ++mt) {
        #pragma unroll
        for (int r = 0; r < 4; ++r) {
            const int rl = mt * 16 + erow + r;
            const int row = bm + rl;
            const float mu = lnstat[rl][0];
            const float rs = lnstat[rl][1];
            if (row < M) {
                #pragma unroll
                for (int nt = 0; nt < 4; ++nt) {
                    const int col = wn + nt * 16 + ecol;
                    const float o = (acc[mt][nt][r] - mu) * rs * g4[nt] + b4[nt];
                    Cout[(size_t)row * 256 + col] = (OutT)o;
                }
            }
        }
    }
}

// ---------------- deformable sampling ----------------
// One token per block, 256 thr = 8 heads x 32 channels. Corner idx pre-scaled to BYTES.
__global__ __launch_bounds__(256) void msda_sample(
    const __bf16* __restrict__ value, // [Mpad, 256] bf16
    const __bf16* __restrict__ oa,    // [Mpad, 384] bf16: [off(256) | attn(128)]
    const float* __restrict__ refp,   // [M, 4, 2]
    __bf16* __restrict__ out)         // [Mpad, 256] bf16
{
    __shared__ uint32_t sc[8][16][8]; // per (h,lp): {i0,w0,i1,w1,i2,w2,i3,w3} ; 4 KB
    __shared__ float sw[8][16];       // softmax weights

    const int row = blockIdx.x;
    const int tid = threadIdx.x;

    uint32_t cidx[4];
    float    cwt[4];
    const int h  = tid >> 4;
    const int lp = tid & 15;

    if (tid < 128) {
        const int l  = lp >> 2;
        const int Ww = c_lvl_w[l];
        const int Hh = c_lvl_h[l];
        const uint32_t opk = *(const uint32_t*)(oa + (size_t)row * 384 + h * 32 + lp * 2);
        const float ox = bflo(opk), oy = bfhi(opk);
        const float rx = refp[((size_t)row * 4 + l) * 2 + 0];
        const float ry = refp[((size_t)row * 4 + l) * 2 + 1];
        const float x = (rx + ox / (float)Ww) * (float)Ww - 0.5f;
        const float y = (ry + oy / (float)Hh) * (float)Hh - 0.5f;
        const float xf = floorf(x), yf = floorf(y);
        const float fx = x - xf,    fy = y - yf;
        const int x0 = (int)xf, y0 = (int)yf;
        const int n  = row / LEN_IN;
        const int base = n * LEN_IN + c_lvl_s[l];
        #pragma unroll
        for (int c = 0; c < 4; ++c) {
            const int dx = c & 1, dy = c >> 1;
            const int xi = x0 + dx, yi = y0 + dy;
            const bool valid = (xi >= 0) & (xi < Ww) & (yi >= 0) & (yi < Hh);
            cidx[c] = valid ? (uint32_t)(base + yi * Ww + xi) * 512u : 0u;   // BYTE offset
            cwt[c]  = valid ? (dx ? fx : 1.f - fx) * (dy ? fy : 1.f - fy) : 0.f;
        }
    } else if (tid < 136) {
        const int h2 = tid - 128;
        const __bf16* ap = oa + (size_t)row * 384 + 256 + h2 * 16;
        float e[16], mx = -1e30f;
        #pragma unroll
        for (int i = 0; i < 16; ++i) { e[i] = (float)ap[i]; mx = fmaxf(mx, e[i]); }
        float s = 0.f;
        #pragma unroll
        for (int i = 0; i < 16; ++i) { e[i] = __expf(e[i] - mx); s += e[i]; }
        const float inv = 1.f / s;
        #pragma unroll
        for (int i = 0; i < 16; ++i) sw[h2][i] = e[i] * inv;
    }
    __syncthreads();
    if (tid < 128) {
        const float a = sw[h][lp];
        u32x4 pk0 = { cidx[0], __float_as_uint(cwt[0] * a), cidx[1], __float_as_uint(cwt[1] * a) };
        u32x4 pk1 = { cidx[2], __float_as_uint(cwt[2] * a), cidx[3], __float_as_uint(cwt[3] * a) };
        *(u32x4*)&sc[h][lp][0] = pk0;
        *(u32x4*)&sc[h][lp][4] = pk1;
    }
    __syncthreads();

    const char* __restrict__ vb = (const char*)value;
    const int gh  = tid >> 5;
    const uint32_t colb = (uint32_t)tid * 2u;   // byte offset of this channel
    float acc = 0.f;
    #pragma unroll
    for (int q = 0; q < 16; ++q) {
        const u32x4 a = *(const u32x4*)&sc[gh][q][0];
        const u32x4 b = *(const u32x4*)&sc[gh][q][4];
        acc += __uint_as_float(a.y) * __uint_as_float((uint32_t)(*(const uint16_t*)(vb + (size_t)(a.x + colb))) << 16);
        acc += __uint_as_float(a.w) * __uint_as_float((uint32_t)(*(const uint16_t*)(vb + (size_t)(a.z + colb))) << 16);
        acc += __uint_as_float(b.y) * __uint_as_float((uint32_t)(*(const uint16_t*)(vb + (size_t)(b.x + colb))) << 16);
        acc += __uint_as_float(b.w) * __uint_as_float((uint32_t)(*(const uint16_t*)(vb + (size_t)(b.z + colb))) << 16);
    }
    out[(size_t)row * 256 + tid] = (__bf16)acc;
}

// ---------------- launch ----------------
extern "C" void kernel_launch(void* const* d_in, const int* in_sizes, int n_in,
                              void* d_out, int out_size, void* d_ws, size_t ws_size,
                              hipStream_t stream)
{
    const float* src     = (const float*)d_in[0];
    const float* pos     = (const float*)d_in[1];
    const float* refp    = (const float*)d_in[2];
    const float* W_value = (const float*)d_in[5];
    const float* b_value = (const float*)d_in[6];
    const float* W_off   = (const float*)d_in[7];
    const float* b_off   = (const float*)d_in[8];
    const float* W_attn  = (const float*)d_in[9];
    const float* b_attn  = (const float*)d_in[10];
    const float* W_out   = (const float*)d_in[11];
    const float* b_out   = (const float*)d_in[12];
    const float* W1      = (const float*)d_in[13];
    const float* b1      = (const float*)d_in[14];
    const float* W2      = (const float*)d_in[15];
    const float* b2      = (const float*)d_in[16];
    const float* g1      = (const float*)d_in[17];
    const float* be1     = (const float*)d_in[18];
    const float* g2      = (const float*)d_in[19];
    const float* be2     = (const float*)d_in[20];
    float* outp = (float*)d_out;

    const int M = M_TOK;
    char* ws = (char*)d_ws;
    const size_t R2 = (size_t)M_PAD * 512;   // bytes of one [Mpad,256] bf16 buffer

    __bf16* src_b = (__bf16*)(ws);                    // [0, R2)
    __bf16* q_b   = (__bf16*)(ws + R2);               // [R2, 2R2)
    __bf16* val_b = (__bf16*)(ws + 2 * R2);           // [2R2, 3R2)
    __bf16* oa    = (__bf16*)(ws + 3 * R2);           // [3R2, 4.5R2)
    __bf16* samp  = (__bf16*)(ws + 9 * R2 / 2);       // [4.5R2, 5.5R2)
    __bf16* x_b   = (__bf16*)(ws + 11 * R2 / 2);      // [5.5R2, 6.5R2)
    __bf16* hbuf  = (__bf16*)(ws);                    // [0, 4R2) overlay (dead by FFN1)
    __bf16* wbase = (__bf16*)(ws + 13 * R2 / 2);
    __bf16* Wt_value = wbase;                          // [256][256]
    __bf16* Wt_oa    = wbase + 65536;                  // [384][256]
    __bf16* Wt_out   = wbase + 163840;                 // [256][256]
    __bf16* Wt1      = wbase + 229376;                 // [1024][256]
    __bf16* Wt2      = wbase + 491520;                 // [256][1024]
    float*  bias_oa  = (float*)(wbase + 753664);       // [384]

    const dim3 blk(256);
    const int n4 = M * 256 / 4;                        // 1,701,632 (exact /256)
    const int gm = M_PAD / 128;                        // 208
    const int gl = M_PAD / 64;                         // 416

    prep<<<dim3(737 + (n4 + 255) / 256), blk, 0, stream>>>(
        W_value, W_off, W_attn, W_out, W1, W2,
        Wt_value, Wt_oa, Wt_oa + 65536, Wt_out, Wt1, Wt2,
        b_off, b_attn, bias_oa,
        (const float4*)src, (const float4*)pos, (bf16x4*)src_b, (bf16x4*)q_b, n4);

    gemm_front<<<dim3(5, gm), blk, 0, stream>>>(
        src_b, Wt_value, b_value, val_b,
        q_b,   Wt_oa,    bias_oa, oa, M);

    msda_sample<<<dim3(M), blk, 0, stream>>>(val_b, oa, refp, samp);

    // x_b = LN(src + samp @ W_out + b_out)  (bf16)
    gemm_ln<__bf16, 256><<<dim3(gl), blk, 0, stream>>>(
        samp, Wt_out, b_out, src_b, g1, be1, x_b, M);

    // hbuf = relu(x_b @ W1 + b1)
    gemm_mfma<__bf16, true, 2, 256><<<dim3(8, gm), blk, 0, stream>>>(x_b, Wt1, b1, hbuf, M, 1024);

    // out = LN(x + hbuf @ W2 + b2)  (fp32, to d_out)
    gemm_ln<float, 1024><<<dim3(gl), blk, 0, stream>>>(
        hbuf, Wt2, b2, x_b, g2, be2, outp, M);
}